// Round 13
// baseline (2615.516 us; speedup 1.0000x reference)
//
#include <hip/hip_runtime.h>
#include <math.h>

#define BSZ 512
#define NV 30
#define NT 24
#define SS 768                  // state row stride (x: 0..249, m: 250..749, pad: 750..767)
#define PL (80 * 24 * 512)      // packed ushorts per (layer, half): 80 nb-blocks x 24 kc x 512
#define NBLK 256
#define NSTEP 144

typedef __attribute__((ext_vector_type(8))) short bf16x8;
typedef __attribute__((ext_vector_type(4))) float f32x4;
typedef __attribute__((ext_vector_type(4))) unsigned u32x4;

__device__ __forceinline__ unsigned short f2bf(float f) {
    unsigned u = __float_as_uint(f);
    u += 0x7fffu + ((u >> 16) & 1u);        // round-to-nearest-even
    return (unsigned short)(u >> 16);
}
__device__ __forceinline__ float bf2f(unsigned short h) {
    return __uint_as_float(((unsigned)h) << 16);
}
__device__ __forceinline__ f32x4 mm(bf16x8 a, bf16x8 b, f32x4 c) {
    return __builtin_amdgcn_mfma_f32_16x16x32_bf16(a, b, c, 0, 0, 0);
}
#define LD8(p) (*(const bf16x8*)(const void*)(p))

// coalesced 16B load, L1-bypass (sc0); result valid only after explicit vmcnt fence.
__device__ __forceinline__ u32x4 ld16_sc0(const void* p) {
    u32x4 r;
    asm volatile("global_load_dwordx4 %0, %1, off sc0" : "=v"(r) : "v"(p) : "memory");
    return r;
}

struct RecArgs {
    const unsigned short* Pw;
    unsigned* A0; unsigned* A1;      // interleaved state planes: elem = hi | (lo<<16)
    float* Sfin;
    unsigned int* flags;             // per-XCD: 16 flags x 32-u32 stride (parallel arrivals)
    unsigned int* rel;               // per-XCD release words, stride 32 u32
    unsigned int* ticket;            // per-XCD tickets [8]
    const float* b1_sw; const float* b1_mem; const float* b1_sv;
    const float* b_sw;  const float* b_mem;  const float* b_sv;
    const float* w1_sw; const float* w1_mem; const float* w1_sv;
    const int* letters;
};

// ---------------- zero ----------------
__global__ void zero_kernel(float* p, int n) {
    int i = blockIdx.x * blockDim.x + threadIdx.x;
    int st = gridDim.x * blockDim.x;
    for (; i < n; i += st) p[i] = 0.f;
}

// ---------------- one-time weight pack (ALL 6 layers, one launch): fp32 -> hi/lo bf16 MFMA-B ----
// Phi[((nb*24 + kc)*64 + lane)*8 + j] = bf16_hi(W[kc*32 + (lane>>4)*8 + j][nb*16 + (lane&15)])
// nb 0..31 = sw (N=500 pad 512), 32..63 = mem, 64..79 = sv (N=250 pad 256). k>=750 zero-padded.
__launch_bounds__(64)
__global__ void pack_weights_all(const float* __restrict__ w1_sw, const float* __restrict__ w1_mem,
                                 const float* __restrict__ w1_sv,
                                 const float* __restrict__ w_sw, const float* __restrict__ w_mem,
                                 const float* __restrict__ w_sv,
                                 unsigned short* __restrict__ Pw)
{
    const int kc = blockIdx.x;   // 0..23
    const int nb = blockIdx.y;   // 0..79
    const int lyr = blockIdx.z;  // 0..5
    const int l  = threadIdx.x;  // 0..63
    const int g = l >> 4, c = l & 15;
    const float *Wsw, *Wmem, *Wsv;
    if (lyr == 0) { Wsw = w1_sw; Wmem = w1_mem; Wsv = w1_sv; }
    else {
        Wsw  = w_sw  + (size_t)(lyr - 1) * 750 * 500;
        Wmem = w_mem + (size_t)(lyr - 1) * 750 * 500;
        Wsv  = w_sv  + (size_t)(lyr - 1) * 750 * 250;
    }
    unsigned short* Phi = Pw + (size_t)lyr * 2 * PL;
    unsigned short* Plo = Phi + PL;
    const float* W; int N, nbl;
    if (nb < 32)      { W = Wsw;  N = 500; nbl = nb; }
    else if (nb < 64) { W = Wmem; N = 500; nbl = nb - 32; }
    else              { W = Wsv;  N = 250; nbl = nb - 64; }
    const int n = nbl * 16 + c;
    unsigned short h8[8], l8[8];
    #pragma unroll
    for (int j = 0; j < 8; ++j) {
        const int k = kc * 32 + g * 8 + j;
        const float w = (k < 750 && n < N) ? W[(size_t)k * N + n] : 0.f;
        const unsigned short h = f2bf(w);
        h8[j] = h;
        l8[j] = f2bf(w - bf2f(h));
    }
    const size_t off = ((size_t)nb * 24 + kc) * 512 + (size_t)l * 8;
    #pragma unroll
    for (int j = 0; j < 8; ++j) { Phi[off + j] = h8[j]; Plo[off + j] = l8[j]; }
}

// ---------------- persistent recurrence: all 24*6 layers in one kernel ----------------
// ROW-PER-XCD (r9-proven) + r13's two changes:
//  (1) rb=2 B-REUSE: each wave computes 32 rows x 16 cols, reading each B fragment once
//      per 32 rows -> per-XCD B-traffic halves (15.7 -> 7.86 MB/step). Exact task fit:
//      16 working blocks/XCD x 6 waves = 96 = 2 row-groups x 48 column units. Block
//      stages its row-group's 32 rows in 96KB LDS (=> 1 block/CU). Launch 256 blocks;
//      capacity = 256 => pigeonhole 32/XCD; tickets j>=16 exit (r8/r9-proven).
//  (2) FLAG-ARRAY BARRIER: arrivals are parallel plain stores to 128B-spaced words
//      (no serialized same-line RMW chain); leader (j==0) polls 15 flags, stores the
//      per-XCD release; others spin on release. Same agent-scope relaxed primitives
//      and vmcnt-drain discipline as r9's proven barrier.
// Per-output MFMA order identical to r3..r12 => absmax canary 2.441e-4 must hold.
__launch_bounds__(384)
__global__ void recurrence(RecArgs A)
{
    __shared__ __align__(16) unsigned char lds[98304];   // [plane 0=hi,1=lo][row 0..31][1536B, XOR-swizzled]
    __shared__ int s_j;
    const int tid = threadIdx.x;

    int xcd;
    asm volatile("s_getreg_b32 %0, hwreg(HW_REG_XCC_ID)" : "=s"(xcd));
    xcd &= 7;
    if (tid == 0) s_j = (int)atomicAdd(A.ticket + xcd, 1u);
    __syncthreads();
    const int j = s_j;                   // 0..31 within this XCD (exact pigeonhole)
    if (j >= 16) return;                 // surplus block
    const int rg = j >> 3, p = j & 7;    // row-group 0..1, column-block 0..7
    const int m0 = xcd * 64 + rg * 32;

    const int w  = tid >> 6;             // wave 0..5
    const int l6 = tid & 63;
    const int g = l6 >> 4, c = l6 & 15;
    const int asw = (c & 7) << 4;        // FRAG XOR bits (row&7 == c&7; rb*16%8==0)

    const int cu = p * 6 + w;            // column unit 0..47
    const bool ispair = (cu < 32);
    const int su = ispair ? cu : (cu - 32);
    const int col = su * 16 + c;         // pair: m-col (valid<500); sv: x-col (valid<250)

    const size_t lnoff = (size_t)l6 * 8;
    const size_t bofs0 = ((size_t)((ispair ? cu : 64 + su) * 24)) * 512 + lnoff;
    const size_t bofs1 = ((size_t)((32 + cu) * 24)) * 512 + lnoff;   // pair only

    unsigned* flagw = A.flags + (size_t)xcd * 16 * 32;   // 16 flags, 128B apart
    unsigned* relw  = A.rel + (xcd << 5);

    float mreg[2][4];
    #pragma unroll
    for (int i = 0; i < 2; ++i)
        #pragma unroll
        for (int r = 0; r < 4; ++r) mreg[i][r] = 0.f;

#define FRAG(pl, rb, kc) (*(const bf16x8*)(lds + (pl) * 49152 + ((rb) * 16 + c) * 1536 + ((((kc) * 64) + g * 16) ^ asw)))

    #pragma unroll 1
    for (int step = 0; step < NSTEP; ++step) {
        const int tt = step / 6;
        const int l = step - 6 * tt;
        const unsigned* Ain = (step & 1) ? A.A1 : A.A0;
        unsigned* Aout      = (step & 1) ? A.A0 : A.A1;
        const unsigned short* Phi = A.Pw + (size_t)l * 2 * PL;
        const unsigned short* Plo = Phi + PL;
        const bool more = (step != NSTEP - 1);

        // ---- stage A rows [m0, m0+32): 32 rows x 192 16B-chunks = 6144 / 384 thr = 16,
        // in two batches of 8 (proven r9 pattern: sc0 dwordx4 + vmcnt fence + unpack).
        {
            const unsigned char* src = (const unsigned char*)(Ain + (size_t)m0 * SS);
            #pragma unroll
            for (int half = 0; half < 2; ++half) {
                u32x4 tmp[8];
                #pragma unroll
                for (int jj = 0; jj < 8; ++jj) {
                    const int f = tid + (half * 8 + jj) * 384;
                    const int row = f / 192;
                    const int q = f - row * 192;
                    tmp[jj] = ld16_sc0(src + row * 3072 + q * 16);
                }
                asm volatile("s_waitcnt vmcnt(0)" ::: "memory");
                __builtin_amdgcn_sched_barrier(0);
                #pragma unroll
                for (int jj = 0; jj < 8; ++jj) {
                    const int f = tid + (half * 8 + jj) * 384;
                    const int row = f / 192;
                    const int q = f - row * 192;
                    const int d = row * 1536 + ((q * 8) ^ ((row & 7) << 4));
                    const u32x4 v = tmp[jj];
                    const unsigned h0 = (v[0] & 0xffffu) | (v[1] << 16);
                    const unsigned h1 = (v[2] & 0xffffu) | (v[3] << 16);
                    const unsigned o0 = (v[0] >> 16) | (v[1] & 0xffff0000u);
                    const unsigned o1 = (v[2] >> 16) | (v[3] & 0xffff0000u);
                    *(unsigned long long*)(lds + d)         = (unsigned long long)h0 | ((unsigned long long)h1 << 32);
                    *(unsigned long long*)(lds + 49152 + d) = (unsigned long long)o0 | ((unsigned long long)o1 << 32);
                }
            }
        }
        __syncthreads();

        if (ispair) {
            f32x4 z0[2], z1[2];
            z0[0] = (f32x4)0.f; z0[1] = (f32x4)0.f;
            z1[0] = (f32x4)0.f; z1[1] = (f32x4)0.f;
            #pragma unroll 4
            for (int kc = 0; kc < 24; ++kc) {
                const bf16x8 ah0 = FRAG(0, 0, kc), ah1 = FRAG(0, 1, kc);
                const bf16x8 al0 = FRAG(1, 0, kc), al1 = FRAG(1, 1, kc);
                const size_t k5 = (size_t)kc * 512;
                const bf16x8 bh0 = LD8(Phi + bofs0 + k5);
                const bf16x8 bl0 = LD8(Plo + bofs0 + k5);
                const bf16x8 bh1 = LD8(Phi + bofs1 + k5);
                const bf16x8 bl1 = LD8(Plo + bofs1 + k5);
                z0[0] = mm(ah0, bh0, z0[0]); z0[0] = mm(al0, bh0, z0[0]); z0[0] = mm(ah0, bl0, z0[0]);
                z0[1] = mm(ah1, bh0, z0[1]); z0[1] = mm(al1, bh0, z0[1]); z0[1] = mm(ah1, bl0, z0[1]);
                z1[0] = mm(ah0, bh1, z1[0]); z1[0] = mm(al0, bh1, z1[0]); z1[0] = mm(ah0, bl1, z1[0]);
                z1[1] = mm(ah1, bh1, z1[1]); z1[1] = mm(al1, bh1, z1[1]); z1[1] = mm(ah1, bl1, z1[1]);
            }
            if (col < 500) {
                const float* bswp  = l ? A.b_sw  + (size_t)(l - 1) * 500 : A.b1_sw;
                const float* bmemp = l ? A.b_mem + (size_t)(l - 1) * 500 : A.b1_mem;
                const float bs = bswp[col];
                const float bm = bmemp[col];
                #pragma unroll
                for (int rb = 0; rb < 2; ++rb) {
                    #pragma unroll
                    for (int r = 0; r < 4; ++r) {
                        const int row = m0 + rb * 16 + g * 4 + r;
                        float zs = z0[rb][r] + bs;
                        float zm = z1[rb][r] + bm;
                        if (l == 0) {
                            const int lt = A.letters[row * NT + tt];
                            zs += A.w1_sw[(size_t)(750 + lt) * 500 + col];
                            zm += A.w1_mem[(size_t)(750 + lt) * 500 + col];
                        }
                        const float s = 1.f / (1.f + expf(-zs));
                        const float mn = mreg[rb][r] * s + tanhf(zm) * (1.f - s);
                        mreg[rb][r] = mn;
                        const size_t o = (size_t)row * SS + 250 + col;
                        const unsigned short h = f2bf(mn);
                        const unsigned short lo2 = f2bf(mn - bf2f(h));
                        Aout[o] = (unsigned)h | ((unsigned)lo2 << 16);   // plain store -> XCD L2
                        if (step == NSTEP - 1) A.Sfin[o] = mn;
                    }
                }
            }
        } else {
            f32x4 z0[2];
            z0[0] = (f32x4)0.f; z0[1] = (f32x4)0.f;
            #pragma unroll 4
            for (int kc = 0; kc < 24; ++kc) {
                const bf16x8 ah0 = FRAG(0, 0, kc), ah1 = FRAG(0, 1, kc);
                const bf16x8 al0 = FRAG(1, 0, kc), al1 = FRAG(1, 1, kc);
                const size_t k5 = (size_t)kc * 512;
                const bf16x8 bh = LD8(Phi + bofs0 + k5);
                const bf16x8 bl = LD8(Plo + bofs0 + k5);
                z0[0] = mm(ah0, bh, z0[0]); z0[0] = mm(al0, bh, z0[0]); z0[0] = mm(ah0, bl, z0[0]);
                z0[1] = mm(ah1, bh, z0[1]); z0[1] = mm(al1, bh, z0[1]); z0[1] = mm(ah1, bl, z0[1]);
            }
            if (col < 250) {
                const float* bsvp = l ? A.b_sv + (size_t)(l - 1) * 250 : A.b1_sv;
                const float bv = bsvp[col];
                #pragma unroll
                for (int rb = 0; rb < 2; ++rb) {
                    #pragma unroll
                    for (int r = 0; r < 4; ++r) {
                        const int row = m0 + rb * 16 + g * 4 + r;
                        float z = z0[rb][r] + bv;
                        if (l == 0) {
                            const int lt = A.letters[row * NT + tt];
                            z += A.w1_sv[(size_t)(750 + lt) * 250 + col];
                        }
                        const float x = tanhf(z);
                        const size_t o = (size_t)row * SS + col;
                        const unsigned short h = f2bf(x);
                        const unsigned short lo2 = f2bf(x - bf2f(h));
                        Aout[o] = (unsigned)h | ((unsigned)lo2 << 16);   // plain store -> XCD L2
                        if (step == NSTEP - 1) A.Sfin[o] = x;
                    }
                }
            }
        }

        // ---- per-XCD flag-array barrier: parallel arrivals, leader polls, RO release ----
        __syncthreads();                 // drains this block's state stores to L2
        if (more) {
            const unsigned tgt = (unsigned)(step + 1);
            if (tid == 0) {
                if (j == 0) {
                    bool all;
                    do {
                        all = true;
                        #pragma unroll
                        for (int b = 1; b < 16; ++b)
                            if (__hip_atomic_load(flagw + b * 32, __ATOMIC_RELAXED, __HIP_MEMORY_SCOPE_AGENT) < tgt)
                                all = false;
                        if (!all) __builtin_amdgcn_s_sleep(1);
                    } while (!all);
                    __hip_atomic_store(relw, tgt, __ATOMIC_RELAXED, __HIP_MEMORY_SCOPE_AGENT);
                } else {
                    __hip_atomic_store(flagw + j * 32, tgt, __ATOMIC_RELAXED, __HIP_MEMORY_SCOPE_AGENT);
                    while (__hip_atomic_load(relw, __ATOMIC_RELAXED, __HIP_MEMORY_SCOPE_AGENT) < tgt)
                        __builtin_amdgcn_s_sleep(2);
                }
            }
            __syncthreads();
        }
    }
#undef FRAG
}

// ---------------- head GEMM: Y = tanh(X @ W + b) (fp32) ----------------
__launch_bounds__(128)
__global__ void head_gemm(const float* __restrict__ X, int ldx, int K,
                          const float* __restrict__ W, const float* __restrict__ bias,
                          float* __restrict__ Y, int N)
{
    const int tid = threadIdx.x;
    const int m0 = blockIdx.y * 32;
    const int n0 = blockIdx.x * 64;

    __shared__ float As[2][32][36];
    __shared__ float Bs[2][32][68];

    const int tx = tid & 15, ty = tid >> 4;
    const int kl = tid & 31, rl = tid >> 5;
    const int cl = tid & 63, kg = tid >> 6;
    const bool cok = (n0 + cl) < N;

    float acc[4][4] = {{0.f}};
    float ar[8], br[16];

    {
        const float* a = X + (size_t)(m0 + rl) * ldx + kl;
        #pragma unroll
        for (int i = 0; i < 8; i++) ar[i] = a[(size_t)(4 * i) * ldx];
        #pragma unroll
        for (int i = 0; i < 16; i++)
            br[i] = cok ? W[(size_t)(kg + 2 * i) * N + n0 + cl] : 0.f;
        #pragma unroll
        for (int i = 0; i < 8; i++) As[0][kl][rl + 4 * i] = ar[i];
        #pragma unroll
        for (int i = 0; i < 16; i++) Bs[0][kg + 2 * i][cl] = br[i];
    }
    __syncthreads();

    int buf = 0;
    const int NK = (K + 31) / 32;
    #pragma unroll 1
    for (int kt = 0; kt < NK; kt++) {
        const bool more = (kt + 1 < NK);
        if (more) {
            const int k0 = (kt + 1) * 32;
            const bool ka = (k0 + kl) < K;
            const float* a = X + (size_t)(m0 + rl) * ldx + k0 + kl;
            #pragma unroll
            for (int i = 0; i < 8; i++) ar[i] = ka ? a[(size_t)(4 * i) * ldx] : 0.f;
            #pragma unroll
            for (int i = 0; i < 16; i++) {
                const int kk = k0 + kg + 2 * i;
                br[i] = (cok && kk < K) ? W[(size_t)kk * N + n0 + cl] : 0.f;
            }
        }
        #pragma unroll
        for (int kk = 0; kk < 32; kk++) {
            float4 av = *(const float4*)&As[buf][kk][ty * 4];
            float4 bv = *(const float4*)&Bs[buf][kk][tx * 4];
            const float aa[4] = {av.x, av.y, av.z, av.w};
            const float bb[4] = {bv.x, bv.y, bv.z, bv.w};
            #pragma unroll
            for (int i = 0; i < 4; i++)
                #pragma unroll
                for (int j = 0; j < 4; j++)
                    acc[i][j] = fmaf(aa[i], bb[j], acc[i][j]);
        }
        if (more) {
            #pragma unroll
            for (int i = 0; i < 8; i++) As[buf ^ 1][kl][rl + 4 * i] = ar[i];
            #pragma unroll
            for (int i = 0; i < 16; i++) Bs[buf ^ 1][kg + 2 * i][cl] = br[i];
            __syncthreads();
            buf ^= 1;
        }
    }

    #pragma unroll
    for (int i = 0; i < 4; i++) {
        const int b = m0 + ty * 4 + i;
        #pragma unroll
        for (int j = 0; j < 4; j++) {
            const int n = n0 + tx * 4 + j;
            if (n < N) Y[(size_t)b * N + n] = tanhf(acc[i][j] + bias[n]);
        }
    }
}

// ---------------- final: logits (K=100, N=30) + softmax ----------------
__global__ void head_final(const float* __restrict__ Y4, const float* __restrict__ W,
                           const float* __restrict__ bias, float* __restrict__ out)
{
    const int row = blockIdx.x;
    __shared__ float y[100];
    __shared__ float z[NV];
    for (int k = threadIdx.x; k < 100; k += 64) y[k] = Y4[row * 100 + k];
    __syncthreads();
    const int n = threadIdx.x;
    if (n < NV) {
        float acc = bias[n];
        for (int k = 0; k < 100; k++) acc = fmaf(y[k], W[k * NV + n], acc);
        z[n] = acc;
    }
    __syncthreads();
    if (n < NV) {
        float mx = -1e30f;
        for (int i = 0; i < NV; i++) mx = fmaxf(mx, z[i]);
        float sum = 0.f;
        for (int i = 0; i < NV; i++) sum += expf(z[i] - mx);
        out[row * NV + n] = expf(z[n] - mx) / sum;
    }
}

extern "C" void kernel_launch(void* const* d_in, const int* in_sizes, int n_in,
                              void* d_out, int out_size, void* d_ws, size_t ws_size,
                              hipStream_t stream)
{
    const int*   letters = (const int*)  d_in[0];
    const float* w1_sv   = (const float*)d_in[1];
    const float* b1_sv   = (const float*)d_in[2];
    const float* w1_mem  = (const float*)d_in[3];
    const float* b1_mem  = (const float*)d_in[4];
    const float* w1_sw   = (const float*)d_in[5];
    const float* b1_sw   = (const float*)d_in[6];
    const float* w_sv    = (const float*)d_in[7];
    const float* b_sv    = (const float*)d_in[8];
    const float* w_mem   = (const float*)d_in[9];
    const float* b_mem   = (const float*)d_in[10];
    const float* w_sw    = (const float*)d_in[11];
    const float* b_sw    = (const float*)d_in[12];
    const float* wp1 = (const float*)d_in[13]; const float* bp1 = (const float*)d_in[14];
    const float* wp2 = (const float*)d_in[15]; const float* bp2 = (const float*)d_in[16];
    const float* wp3 = (const float*)d_in[17]; const float* bp3 = (const float*)d_in[18];
    const float* wp4 = (const float*)d_in[19]; const float* bp4 = (const float*)d_in[20];
    const float* wp5 = (const float*)d_in[21]; const float* bp5 = (const float*)d_in[22];

    // workspace layout
    float* Sfin = (float*)d_ws;                                   // BSZ*SS f32 (written at final step)
    float* cntf = Sfin + (size_t)BSZ * SS;                        // 8192 u32: flags[8x16x32], rel[8x32], ticket[8]
    unsigned int* flags  = (unsigned int*)cntf;                   // 4096 u32
    unsigned int* rel    = flags + 4096;                          // 256 u32
    unsigned int* ticket = flags + 4352;                          // 8 u32
    unsigned* A0 = (unsigned*)(cntf + 8192);                      // interleaved state plane 0
    unsigned* A1 = A0 + (size_t)BSZ * SS;                         // interleaved state plane 1
    unsigned short* Pw = (unsigned short*)(A1 + (size_t)BSZ * SS);// 12 * PL ushorts
    float* Y1 = (float*)(Pw + (size_t)12 * PL);
    float* Y2 = Y1 + (size_t)BSZ * 450;
    float* Y3 = Y2 + (size_t)BSZ * 300;
    float* Y4 = Y3 + (size_t)BSZ * 200;

    // zero barrier words + tickets + both interleaved state planes (pad cols stay 0 forever)
    zero_kernel<<<512, 256, 0, stream>>>(cntf, 8192 + 2 * BSZ * SS);

    // one-time weight packing: single launch, all 6 layers
    pack_weights_all<<<dim3(24, 80, 6), 64, 0, stream>>>(w1_sw, w1_mem, w1_sv,
                                                         w_sw, w_mem, w_sv, Pw);

    RecArgs ra;
    ra.Pw = Pw;
    ra.A0 = A0; ra.A1 = A1;
    ra.Sfin = Sfin; ra.flags = flags; ra.rel = rel; ra.ticket = ticket;
    ra.b1_sw = b1_sw; ra.b1_mem = b1_mem; ra.b1_sv = b1_sv;
    ra.b_sw = b_sw;   ra.b_mem = b_mem;   ra.b_sv = b_sv;
    ra.w1_sw = w1_sw; ra.w1_mem = w1_mem; ra.w1_sv = w1_sv;
    ra.letters = letters;
    recurrence<<<NBLK, 384, 0, stream>>>(ra);

    head_gemm<<<dim3(8, 16), 128, 0, stream>>>(Sfin, SS, 750, wp1, bp1, Y1, 450);
    head_gemm<<<dim3(5, 16), 128, 0, stream>>>(Y1, 450, 450, wp2, bp2, Y2, 300);
    head_gemm<<<dim3(4, 16), 128, 0, stream>>>(Y2, 300, 300, wp3, bp3, Y3, 200);
    head_gemm<<<dim3(2, 16), 128, 0, stream>>>(Y3, 200, 200, wp4, bp4, Y4, 100);
    head_final<<<BSZ, 64, 0, stream>>>(Y4, wp5, bp5, (float*)d_out);
}

// Round 15
// 2058.775 us; speedup vs baseline: 1.2704x; 1.2704x over previous
//
#include <hip/hip_runtime.h>
#include <math.h>

#define BSZ 512
#define NV 30
#define NT 24
#define SS 768                  // state row stride (x: 0..249, m: 250..749, pad: 750..767)
#define PL (80 * 24 * 512)      // packed ushorts per (layer, half): 80 nb-blocks x 24 kc x 512
#define NBLK 256
#define NSTEP 144

typedef __attribute__((ext_vector_type(8))) short bf16x8;
typedef __attribute__((ext_vector_type(4))) float f32x4;
typedef __attribute__((ext_vector_type(4))) unsigned u32x4;

__device__ __forceinline__ unsigned short f2bf(float f) {
    unsigned u = __float_as_uint(f);
    u += 0x7fffu + ((u >> 16) & 1u);        // round-to-nearest-even
    return (unsigned short)(u >> 16);
}
__device__ __forceinline__ float bf2f(unsigned short h) {
    return __uint_as_float(((unsigned)h) << 16);
}
__device__ __forceinline__ f32x4 mm(bf16x8 a, bf16x8 b, f32x4 c) {
    return __builtin_amdgcn_mfma_f32_16x16x32_bf16(a, b, c, 0, 0, 0);
}
#define LD8(p) (*(const bf16x8*)(const void*)(p))

// coalesced 16B load, L1-bypass (sc0); result valid only after explicit vmcnt fence.
__device__ __forceinline__ u32x4 ld16_sc0(const void* p) {
    u32x4 r;
    asm volatile("global_load_dwordx4 %0, %1, off sc0" : "=v"(r) : "v"(p) : "memory");
    return r;
}

struct RecArgs {
    const unsigned short* Pw;
    unsigned* A0; unsigned* A1;      // interleaved state planes: elem = hi | (lo<<16)
    float* Sfin;
    unsigned int* flags;             // per (xcd,quarter): 8 flags x 32-u32 stride
    unsigned int* rel;               // per (xcd,quarter) release word, stride 32 u32
    unsigned int* ticket;            // per-XCD tickets [8]
    const float* b1_sw; const float* b1_mem; const float* b1_sv;
    const float* b_sw;  const float* b_mem;  const float* b_sv;
    const float* w1_sw; const float* w1_mem; const float* w1_sv;
    const int* letters;
};

// ---------------- zero ----------------
__global__ void zero_kernel(float* p, int n) {
    int i = blockIdx.x * blockDim.x + threadIdx.x;
    int st = gridDim.x * blockDim.x;
    for (; i < n; i += st) p[i] = 0.f;
}

// ---------------- one-time weight pack (ALL 6 layers, one launch): fp32 -> hi/lo bf16 MFMA-B ----
// Phi[((nb*24 + kc)*64 + lane)*8 + j] = bf16_hi(W[kc*32 + (lane>>4)*8 + j][nb*16 + (lane&15)])
// nb 0..31 = sw (N=500 pad 512), 32..63 = mem, 64..79 = sv (N=250 pad 256). k>=750 zero-padded.
__launch_bounds__(64)
__global__ void pack_weights_all(const float* __restrict__ w1_sw, const float* __restrict__ w1_mem,
                                 const float* __restrict__ w1_sv,
                                 const float* __restrict__ w_sw, const float* __restrict__ w_mem,
                                 const float* __restrict__ w_sv,
                                 unsigned short* __restrict__ Pw)
{
    const int kc = blockIdx.x;   // 0..23
    const int nb = blockIdx.y;   // 0..79
    const int lyr = blockIdx.z;  // 0..5
    const int l  = threadIdx.x;  // 0..63
    const int g = l >> 4, c = l & 15;
    const float *Wsw, *Wmem, *Wsv;
    if (lyr == 0) { Wsw = w1_sw; Wmem = w1_mem; Wsv = w1_sv; }
    else {
        Wsw  = w_sw  + (size_t)(lyr - 1) * 750 * 500;
        Wmem = w_mem + (size_t)(lyr - 1) * 750 * 500;
        Wsv  = w_sv  + (size_t)(lyr - 1) * 750 * 250;
    }
    unsigned short* Phi = Pw + (size_t)lyr * 2 * PL;
    unsigned short* Plo = Phi + PL;
    const float* W; int N, nbl;
    if (nb < 32)      { W = Wsw;  N = 500; nbl = nb; }
    else if (nb < 64) { W = Wmem; N = 500; nbl = nb - 32; }
    else              { W = Wsv;  N = 250; nbl = nb - 64; }
    const int n = nbl * 16 + c;
    unsigned short h8[8], l8[8];
    #pragma unroll
    for (int j = 0; j < 8; ++j) {
        const int k = kc * 32 + g * 8 + j;
        const float w = (k < 750 && n < N) ? W[(size_t)k * N + n] : 0.f;
        const unsigned short h = f2bf(w);
        h8[j] = h;
        l8[j] = f2bf(w - bf2f(h));
    }
    const size_t off = ((size_t)nb * 24 + kc) * 512 + (size_t)l * 8;
    #pragma unroll
    for (int j = 0; j < 8; ++j) { Phi[off + j] = h8[j]; Plo[off + j] = l8[j]; }
}

// ---------------- persistent recurrence: all 24*6 layers in one kernel ----------------
// RETRY of r14 (identical logic): r14's "container failed twice" matches r10's opaque
// infra signature, not r4's genuine-failure signature (pytest assertion). Audit found no
// deadlock mode that wouldn't also have broken r9/r11/r12/r13's ticket barriers:
// quarter groups are closed (each row's update reads only that row's own state), LDS
// 82432B forces 1 block/CU => exact 32/XCD pigeonhole, flags are monotone counters.
// Pre-committed: pass => quarter-barrier validated; fail-twice => kernel hang, revert.
// Structure: ROW-PER-XCD (r9-proven). Block j of XCD: quarter=j>>3 (16 rows), p=j&7;
// wave w -> column task p*6+w of 48. State via plain stores -> XCD L2 + sc0 loads.
// r14 change: QUARTER-LOCAL 8-participant flag-array barrier (7 parallel flag stores +
// leader polls 7 + one release word) -- skew no longer globalizes across quarters/XCDs.
// Per-output MFMA order identical to r3..r13 => absmax canary 2.441e-4 must hold.
__launch_bounds__(384)
__global__ void recurrence(RecArgs A)
{
    __shared__ __align__(16) unsigned char lds[81920];   // 48KB used; 80KB forces 1 block/CU
    __shared__ int s_j;
    const int tid = threadIdx.x;

    int xcd;
    asm volatile("s_getreg_b32 %0, hwreg(HW_REG_XCC_ID)" : "=s"(xcd));
    xcd &= 7;
    if (tid == 0) s_j = (int)atomicAdd(A.ticket + xcd, 1u);
    __syncthreads();
    const int j = s_j;                   // 0..31 within this XCD (exact pigeonhole)
    const int quarter = j >> 3, p = j & 7;
    const int m0 = xcd * 64 + quarter * 16;

    const int w  = tid >> 6;             // wave 0..5
    const int l6 = tid & 63;
    const int g = l6 >> 4, c = l6 & 15;
    const int asw = (c & 7) << 4;        // FRAG XOR bits (row&7 == c&7)

    const int tk = p * 6 + w;            // column task 0..47
    const bool ispair = (tk < 32);
    const int su = ispair ? tk : (tk - 32);
    const int col = su * 16 + c;         // pair: m-col (valid<500); sv: x-col (valid<250)

    const size_t lnoff = (size_t)l6 * 8;
    const size_t bofs0 = ((size_t)((ispair ? tk : 64 + su) * 24)) * 512 + lnoff;
    const size_t bofs1 = ((size_t)((32 + tk) * 24)) * 512 + lnoff;   // pair only

    const int qid = xcd * 4 + quarter;                   // 0..31 quarter-group id
    unsigned* flagq = A.flags + (size_t)qid * 8 * 32;    // 8 flags, 128B apart
    unsigned* relq  = A.rel + (size_t)qid * 32;

    float mreg[4];
    #pragma unroll
    for (int i = 0; i < 4; ++i) mreg[i] = 0.f;

#define FRAG(pl, kc) (*(const bf16x8*)(lds + (pl) * 24576 + c * 1536 + ((((kc) * 64) + g * 16) ^ asw)))

    #pragma unroll 1
    for (int step = 0; step < NSTEP; ++step) {
        const int tt = step / 6;
        const int l = step - 6 * tt;
        const unsigned* Ain = (step & 1) ? A.A1 : A.A0;
        unsigned* Aout      = (step & 1) ? A.A0 : A.A1;
        const unsigned short* Phi = A.Pw + (size_t)l * 2 * PL;
        const unsigned short* Plo = Phi + PL;
        const bool more = (step != NSTEP - 1);

        // ---- stage A rows [m0, m0+16): 16 rows x 3072B = 3072 16B-chunks / 384 thr = 8
        // coalesced sc0 dwordx4 loads per thread; explicit vmcnt fence; unpack hi/lo.
        {
            const unsigned char* src = (const unsigned char*)(Ain + (size_t)m0 * SS);
            u32x4 tmp[8];
            #pragma unroll
            for (int jj = 0; jj < 8; ++jj) {
                const int f = tid + jj * 384;
                const int row = f / 192;
                const int q = f - row * 192;
                tmp[jj] = ld16_sc0(src + row * 3072 + q * 16);
            }
            asm volatile("s_waitcnt vmcnt(0)" ::: "memory");
            __builtin_amdgcn_sched_barrier(0);
            #pragma unroll
            for (int jj = 0; jj < 8; ++jj) {
                const int f = tid + jj * 384;
                const int row = f / 192;
                const int q = f - row * 192;
                const int d = row * 1536 + ((q * 8) ^ ((row & 7) << 4));
                const u32x4 v = tmp[jj];
                const unsigned h0 = (v[0] & 0xffffu) | (v[1] << 16);
                const unsigned h1 = (v[2] & 0xffffu) | (v[3] << 16);
                const unsigned o0 = (v[0] >> 16) | (v[1] & 0xffff0000u);
                const unsigned o1 = (v[2] >> 16) | (v[3] & 0xffff0000u);
                *(unsigned long long*)(lds + d)         = (unsigned long long)h0 | ((unsigned long long)h1 << 32);
                *(unsigned long long*)(lds + 24576 + d) = (unsigned long long)o0 | ((unsigned long long)o1 << 32);
            }
        }
        __syncthreads();

        if (ispair) {
            f32x4 z0 = (f32x4)0.f, z1 = (f32x4)0.f;
            #pragma unroll 4
            for (int kc = 0; kc < 24; ++kc) {
                const bf16x8 ah = FRAG(0, kc);
                const bf16x8 al = FRAG(1, kc);
                const size_t k5 = (size_t)kc * 512;
                const bf16x8 bh0 = LD8(Phi + bofs0 + k5);
                const bf16x8 bl0 = LD8(Plo + bofs0 + k5);
                const bf16x8 bh1 = LD8(Phi + bofs1 + k5);
                const bf16x8 bl1 = LD8(Plo + bofs1 + k5);
                z0 = mm(ah, bh0, z0); z0 = mm(al, bh0, z0); z0 = mm(ah, bl0, z0);
                z1 = mm(ah, bh1, z1); z1 = mm(al, bh1, z1); z1 = mm(ah, bl1, z1);
            }
            if (col < 500) {
                const float* bswp  = l ? A.b_sw  + (size_t)(l - 1) * 500 : A.b1_sw;
                const float* bmemp = l ? A.b_mem + (size_t)(l - 1) * 500 : A.b1_mem;
                const float bs = bswp[col];
                const float bm = bmemp[col];
                #pragma unroll
                for (int r = 0; r < 4; ++r) {
                    const int row = m0 + g * 4 + r;
                    float zs = z0[r] + bs;
                    float zm = z1[r] + bm;
                    if (l == 0) {
                        const int lt = A.letters[row * NT + tt];
                        zs += A.w1_sw[(size_t)(750 + lt) * 500 + col];
                        zm += A.w1_mem[(size_t)(750 + lt) * 500 + col];
                    }
                    const float s = 1.f / (1.f + expf(-zs));
                    const float mn = mreg[r] * s + tanhf(zm) * (1.f - s);
                    mreg[r] = mn;
                    const size_t o = (size_t)row * SS + 250 + col;
                    const unsigned short h = f2bf(mn);
                    const unsigned short lo2 = f2bf(mn - bf2f(h));
                    Aout[o] = (unsigned)h | ((unsigned)lo2 << 16);   // plain store -> XCD L2
                    if (step == NSTEP - 1) A.Sfin[o] = mn;
                }
            }
        } else {
            f32x4 z0 = (f32x4)0.f;
            #pragma unroll 4
            for (int kc = 0; kc < 24; ++kc) {
                const bf16x8 ah = FRAG(0, kc);
                const bf16x8 al = FRAG(1, kc);
                const size_t k5 = (size_t)kc * 512;
                const bf16x8 bh = LD8(Phi + bofs0 + k5);
                const bf16x8 bl = LD8(Plo + bofs0 + k5);
                z0 = mm(ah, bh, z0); z0 = mm(al, bh, z0); z0 = mm(ah, bl, z0);
            }
            if (col < 250) {
                const float* bsvp = l ? A.b_sv + (size_t)(l - 1) * 250 : A.b1_sv;
                const float bv = bsvp[col];
                #pragma unroll
                for (int r = 0; r < 4; ++r) {
                    const int row = m0 + g * 4 + r;
                    float z = z0[r] + bv;
                    if (l == 0) {
                        const int lt = A.letters[row * NT + tt];
                        z += A.w1_sv[(size_t)(750 + lt) * 250 + col];
                    }
                    const float x = tanhf(z);
                    const size_t o = (size_t)row * SS + col;
                    const unsigned short h = f2bf(x);
                    const unsigned short lo2 = f2bf(x - bf2f(h));
                    Aout[o] = (unsigned)h | ((unsigned)lo2 << 16);   // plain store -> XCD L2
                    if (step == NSTEP - 1) A.Sfin[o] = x;
                }
            }
        }

        // ---- quarter-local barrier: 8 participants (the closed dependency group).
        // Parallel flag stores (p=1..7), leader p==0 polls 7 flags then stores release.
        __syncthreads();                 // drains this block's state stores to L2
        if (more) {
            const unsigned tgt = (unsigned)(step + 1);
            if (tid == 0) {
                if (p == 0) {
                    bool all;
                    do {
                        all = true;
                        #pragma unroll
                        for (int b = 1; b < 8; ++b)
                            if (__hip_atomic_load(flagq + b * 32, __ATOMIC_RELAXED, __HIP_MEMORY_SCOPE_AGENT) < tgt)
                                all = false;
                        if (!all) __builtin_amdgcn_s_sleep(2);
                    } while (!all);
                    __hip_atomic_store(relq, tgt, __ATOMIC_RELAXED, __HIP_MEMORY_SCOPE_AGENT);
                } else {
                    __hip_atomic_store(flagq + p * 32, tgt, __ATOMIC_RELAXED, __HIP_MEMORY_SCOPE_AGENT);
                    while (__hip_atomic_load(relq, __ATOMIC_RELAXED, __HIP_MEMORY_SCOPE_AGENT) < tgt)
                        __builtin_amdgcn_s_sleep(2);
                }
            }
            __syncthreads();
        }
    }
#undef FRAG
}

// ---------------- head GEMM: Y = tanh(X @ W + b) (fp32) ----------------
__launch_bounds__(128)
__global__ void head_gemm(const float* __restrict__ X, int ldx, int K,
                          const float* __restrict__ W, const float* __restrict__ bias,
                          float* __restrict__ Y, int N)
{
    const int tid = threadIdx.x;
    const int m0 = blockIdx.y * 32;
    const int n0 = blockIdx.x * 64;

    __shared__ float As[2][32][36];
    __shared__ float Bs[2][32][68];

    const int tx = tid & 15, ty = tid >> 4;
    const int kl = tid & 31, rl = tid >> 5;
    const int cl = tid & 63, kg = tid >> 6;
    const bool cok = (n0 + cl) < N;

    float acc[4][4] = {{0.f}};
    float ar[8], br[16];

    {
        const float* a = X + (size_t)(m0 + rl) * ldx + kl;
        #pragma unroll
        for (int i = 0; i < 8; i++) ar[i] = a[(size_t)(4 * i) * ldx];
        #pragma unroll
        for (int i = 0; i < 16; i++)
            br[i] = cok ? W[(size_t)(kg + 2 * i) * N + n0 + cl] : 0.f;
        #pragma unroll
        for (int i = 0; i < 8; i++) As[0][kl][rl + 4 * i] = ar[i];
        #pragma unroll
        for (int i = 0; i < 16; i++) Bs[0][kg + 2 * i][cl] = br[i];
    }
    __syncthreads();

    int buf = 0;
    const int NK = (K + 31) / 32;
    #pragma unroll 1
    for (int kt = 0; kt < NK; kt++) {
        const bool more = (kt + 1 < NK);
        if (more) {
            const int k0 = (kt + 1) * 32;
            const bool ka = (k0 + kl) < K;
            const float* a = X + (size_t)(m0 + rl) * ldx + k0 + kl;
            #pragma unroll
            for (int i = 0; i < 8; i++) ar[i] = ka ? a[(size_t)(4 * i) * ldx] : 0.f;
            #pragma unroll
            for (int i = 0; i < 16; i++) {
                const int kk = k0 + kg + 2 * i;
                br[i] = (cok && kk < K) ? W[(size_t)kk * N + n0 + cl] : 0.f;
            }
        }
        #pragma unroll
        for (int kk = 0; kk < 32; kk++) {
            float4 av = *(const float4*)&As[buf][kk][ty * 4];
            float4 bv = *(const float4*)&Bs[buf][kk][tx * 4];
            const float aa[4] = {av.x, av.y, av.z, av.w};
            const float bb[4] = {bv.x, bv.y, bv.z, bv.w};
            #pragma unroll
            for (int i = 0; i < 4; i++)
                #pragma unroll
                for (int j = 0; j < 4; j++)
                    acc[i][j] = fmaf(aa[i], bb[j], acc[i][j]);
        }
        if (more) {
            #pragma unroll
            for (int i = 0; i < 8; i++) As[buf ^ 1][kl][rl + 4 * i] = ar[i];
            #pragma unroll
            for (int i = 0; i < 16; i++) Bs[buf ^ 1][kg + 2 * i][cl] = br[i];
            __syncthreads();
            buf ^= 1;
        }
    }

    #pragma unroll
    for (int i = 0; i < 4; i++) {
        const int b = m0 + ty * 4 + i;
        #pragma unroll
        for (int j = 0; j < 4; j++) {
            const int n = n0 + tx * 4 + j;
            if (n < N) Y[(size_t)b * N + n] = tanhf(acc[i][j] + bias[n]);
        }
    }
}

// ---------------- final: logits (K=100, N=30) + softmax ----------------
__global__ void head_final(const float* __restrict__ Y4, const float* __restrict__ W,
                           const float* __restrict__ bias, float* __restrict__ out)
{
    const int row = blockIdx.x;
    __shared__ float y[100];
    __shared__ float z[NV];
    for (int k = threadIdx.x; k < 100; k += 64) y[k] = Y4[row * 100 + k];
    __syncthreads();
    const int n = threadIdx.x;
    if (n < NV) {
        float acc = bias[n];
        for (int k = 0; k < 100; k++) acc = fmaf(y[k], W[k * NV + n], acc);
        z[n] = acc;
    }
    __syncthreads();
    if (n < NV) {
        float mx = -1e30f;
        for (int i = 0; i < NV; i++) mx = fmaxf(mx, z[i]);
        float sum = 0.f;
        for (int i = 0; i < NV; i++) sum += expf(z[i] - mx);
        out[row * NV + n] = expf(z[n] - mx) / sum;
    }
}

extern "C" void kernel_launch(void* const* d_in, const int* in_sizes, int n_in,
                              void* d_out, int out_size, void* d_ws, size_t ws_size,
                              hipStream_t stream)
{
    const int*   letters = (const int*)  d_in[0];
    const float* w1_sv   = (const float*)d_in[1];
    const float* b1_sv   = (const float*)d_in[2];
    const float* w1_mem  = (const float*)d_in[3];
    const float* b1_mem  = (const float*)d_in[4];
    const float* w1_sw   = (const float*)d_in[5];
    const float* b1_sw   = (const float*)d_in[6];
    const float* w_sv    = (const float*)d_in[7];
    const float* b_sv    = (const float*)d_in[8];
    const float* w_mem   = (const float*)d_in[9];
    const float* b_mem   = (const float*)d_in[10];
    const float* w_sw    = (const float*)d_in[11];
    const float* b_sw    = (const float*)d_in[12];
    const float* wp1 = (const float*)d_in[13]; const float* bp1 = (const float*)d_in[14];
    const float* wp2 = (const float*)d_in[15]; const float* bp2 = (const float*)d_in[16];
    const float* wp3 = (const float*)d_in[17]; const float* bp3 = (const float*)d_in[18];
    const float* wp4 = (const float*)d_in[19]; const float* bp4 = (const float*)d_in[20];
    const float* wp5 = (const float*)d_in[21]; const float* bp5 = (const float*)d_in[22];

    // workspace layout
    float* Sfin = (float*)d_ws;                                   // BSZ*SS f32 (written at final step)
    float* cntf = Sfin + (size_t)BSZ * SS;                        // ctrl: flags[32q x 8 x 32], rel[32q x 32], ticket[8]
    unsigned int* flags  = (unsigned int*)cntf;                   // 32*8*32 = 8192 u32
    unsigned int* rel    = flags + 8192;                          // 32*32 = 1024 u32
    unsigned int* ticket = rel + 1024;                            // 8 u32
    unsigned* A0 = (unsigned*)(cntf + 10240);                     // interleaved state plane 0
    unsigned* A1 = A0 + (size_t)BSZ * SS;                         // interleaved state plane 1
    unsigned short* Pw = (unsigned short*)(A1 + (size_t)BSZ * SS);// 12 * PL ushorts
    float* Y1 = (float*)(Pw + (size_t)12 * PL);
    float* Y2 = Y1 + (size_t)BSZ * 450;
    float* Y3 = Y2 + (size_t)BSZ * 300;
    float* Y4 = Y3 + (size_t)BSZ * 200;

    // zero ctrl words + both interleaved state planes (pad cols stay 0 forever)
    zero_kernel<<<512, 256, 0, stream>>>(cntf, 10240 + 2 * BSZ * SS);

    // one-time weight packing: single launch, all 6 layers
    pack_weights_all<<<dim3(24, 80, 6), 64, 0, stream>>>(w1_sw, w1_mem, w1_sv,
                                                         w_sw, w_mem, w_sv, Pw);

    RecArgs ra;
    ra.Pw = Pw;
    ra.A0 = A0; ra.A1 = A1;
    ra.Sfin = Sfin; ra.flags = flags; ra.rel = rel; ra.ticket = ticket;
    ra.b1_sw = b1_sw; ra.b1_mem = b1_mem; ra.b1_sv = b1_sv;
    ra.b_sw = b_sw;   ra.b_mem = b_mem;   ra.b_sv = b_sv;
    ra.w1_sw = w1_sw; ra.w1_mem = w1_mem; ra.w1_sv = w1_sv;
    ra.letters = letters;
    recurrence<<<NBLK, 384, 0, stream>>>(ra);

    head_gemm<<<dim3(8, 16), 128, 0, stream>>>(Sfin, SS, 750, wp1, bp1, Y1, 450);
    head_gemm<<<dim3(5, 16), 128, 0, stream>>>(Y1, 450, 450, wp2, bp2, Y2, 300);
    head_gemm<<<dim3(4, 16), 128, 0, stream>>>(Y2, 300, 300, wp3, bp3, Y3, 200);
    head_gemm<<<dim3(2, 16), 128, 0, stream>>>(Y3, 200, 200, wp4, bp4, Y4, 100);
    head_final<<<BSZ, 64, 0, stream>>>(Y4, wp5, bp5, (float*)d_out);
}